// Round 3
// baseline (998.914 us; speedup 1.0000x reference)
//
#include <hip/hip_runtime.h>

typedef float   f32x4 __attribute__((ext_vector_type(4)));
typedef _Float16 f16x8 __attribute__((ext_vector_type(8)));
typedef short   s16x8 __attribute__((ext_vector_type(8)));
typedef short   s16x4 __attribute__((ext_vector_type(4)));
typedef unsigned short u16;

#define NTOK 8192
#define CDIM 2048
#define NEXP 8
#define NASS 16384   // NTOK * TOP_K

#define GLOBAL_AS __attribute__((address_space(1)))
#define LDS_AS    __attribute__((address_space(3)))

__device__ __forceinline__ u16 f2h_bits(float f) {
  _Float16 h = (_Float16)f;
  union { _Float16 h; u16 u; } v;
  v.h = h;
  return v.u;
}

// ---------- router: fp32 logits, top-2, softmax, counts, x -> f16 ----------
__global__ __launch_bounds__(256) void moe_router(
    const float* __restrict__ x, const float* __restrict__ wr,
    u16* __restrict__ xh, int* __restrict__ top_idx,
    float* __restrict__ top_p, int* __restrict__ counts)
{
  const int wave = threadIdx.x >> 6, lane = threadIdx.x & 63;
  const int n = blockIdx.x * 4 + wave;            // one wave per token
  const float* xr = x + (size_t)n * CDIM;
  u16* xhr = xh + (size_t)n * CDIM;
  float acc[NEXP] = {};
  #pragma unroll
  for (int i = 0; i < CDIM / 256; ++i) {
    const int c = i * 256 + lane * 4;
    const f32x4 xv = *(const f32x4*)(xr + c);
    s16x4 hv;
    #pragma unroll
    for (int j = 0; j < 4; ++j) hv[j] = (short)f2h_bits(xv[j]);
    *(s16x4*)(xhr + c) = hv;                      // fused x -> f16 (8B store)
    #pragma unroll
    for (int j = 0; j < 4; ++j) {
      const f32x4 w0 = *(const f32x4*)(wr + (size_t)(c + j) * NEXP);
      const f32x4 w1 = *(const f32x4*)(wr + (size_t)(c + j) * NEXP + 4);
      #pragma unroll
      for (int e = 0; e < 4; ++e) { acc[e] += xv[j] * w0[e]; acc[4 + e] += xv[j] * w1[e]; }
    }
  }
  #pragma unroll
  for (int off = 32; off > 0; off >>= 1) {
    #pragma unroll
    for (int e = 0; e < NEXP; ++e) acc[e] += __shfl_xor(acc[e], off);
  }
  if (lane == 0) {
    int i0 = 0; float v0 = acc[0];
    #pragma unroll
    for (int e = 1; e < NEXP; ++e) { if (acc[e] > v0) { v0 = acc[e]; i0 = e; } }
    int i1 = -1; float v1 = -3.4e38f;
    #pragma unroll
    for (int e = 0; e < NEXP; ++e) { if (e != i0 && acc[e] > v1) { v1 = acc[e]; i1 = e; } }
    const float ex = __expf(v1 - v0);             // softmax over the 2 kept logits
    const float p0 = 1.f / (1.f + ex);
    top_idx[n * 2 + 0] = i0; top_idx[n * 2 + 1] = i1;
    top_p[n * 2 + 0] = p0;   top_p[n * 2 + 1] = 1.f - p0;
    atomicAdd(&counts[i0], 1);
    atomicAdd(&counts[i1], 1);
  }
}

// ---------- exclusive scan of 8 counts ----------
__global__ void moe_offsets(const int* __restrict__ counts,
                            int* __restrict__ offs, int* __restrict__ fill)
{
  if (threadIdx.x == 0) {
    int s = 0;
    for (int e = 0; e < NEXP; ++e) { offs[e] = s; fill[e] = s; s += counts[e]; }
    offs[NEXP] = s;
  }
}

// ---------- scatter (token, prob) into expert buckets ----------
__global__ __launch_bounds__(256) void moe_scatter(
    const int* __restrict__ top_idx, const float* __restrict__ top_p,
    int* fill, int* __restrict__ tok_s, float* __restrict__ prb_s)
{
  const int n = blockIdx.x * 256 + threadIdx.x;
  #pragma unroll
  for (int k = 0; k < 2; ++k) {
    const int e = top_idx[n * 2 + k];
    const int pos = atomicAdd(&fill[e], 1);
    tok_s[pos] = n;
    prb_s[pos] = top_p[n * 2 + k];
  }
}

// ---------- transpose+convert: w [E][K][N] fp32 -> wT [E][N][K] f16 ----------
__global__ __launch_bounds__(256) void moe_transpose(
    const float* __restrict__ wfc, const float* __restrict__ wpj,
    u16* __restrict__ wfcT, u16* __restrict__ wpjT)
{
  const float* src = blockIdx.z ? wpj : wfc;
  u16* dst = blockIdx.z ? wpjT : wfcT;
  const int e = blockIdx.y;
  src += (size_t)e * CDIM * CDIM;
  dst += (size_t)e * CDIM * CDIM;
  const int tr = (blockIdx.x >> 5) * 64;   // src row (K) base
  const int tc = (blockIdx.x & 31) * 64;   // src col (N) base
  __shared__ float lds[64][65];            // +1 pad breaks bank conflicts
  const int t = threadIdx.x;
  #pragma unroll
  for (int p = 0; p < 4; ++p) {
    const int r  = p * 16 + (t >> 4);
    const int c4 = (t & 15) * 4;
    const f32x4 v = *(const f32x4*)(src + (size_t)(tr + r) * CDIM + tc + c4);
    #pragma unroll
    for (int j = 0; j < 4; ++j) lds[r][c4 + j] = v[j];
  }
  __syncthreads();
  const int d  = t >> 2;
  const int cs = (t & 3) * 16;
  s16x8 o0, o1;
  #pragma unroll
  for (int j = 0; j < 8; ++j) o0[j] = (short)f2h_bits(lds[cs + j][d]);
  #pragma unroll
  for (int j = 0; j < 8; ++j) o1[j] = (short)f2h_bits(lds[cs + 8 + j][d]);
  u16* drow = dst + (size_t)(tc + d) * CDIM + tr + cs;
  *(s16x8*)(drow + 0) = o0;
  *(s16x8*)(drow + 8) = o1;
}

// ---------- grouped GEMM: 256x256 tile, BK=32, 4-buffer counted-vmcnt pipeline ----------
// T3+T4: 2 phases/K-tile, 16 MFMA per barrier-pair, prefetch distance 3 tiles,
// steady-state vmcnt(8) (2 tiles in flight, never drains). T5 setprio around MFMA.
// LDS chunk-major [plane=k-chunk][256 rows][8 u16] + 8-u16 inter-plane pad:
// ds_read_b128 16B-class = (g+rsel) mod 8 -> perfectly even, conflict-free, no XOR.
// MODE 0: H[s,:] = f16(relu(Xg @ WfcT^T)^2)   (A = xh gathered via tok_s)
// MODE 1: out[tok,:] += prb * (H @ WpjT^T)    (A = h linear; atomic combine)
template<int MODE>
__global__ __launch_bounds__(512, 2) void moe_gemm3(
    const u16* __restrict__ A, const u16* __restrict__ W,
    const int* __restrict__ tok_s, const float* __restrict__ prb_s,
    const int* __restrict__ offs, u16* __restrict__ hout,
    float* __restrict__ out)
{
  const int e     = blockIdx.y >> 5;          // 32 m-tiles per expert (Me <= 8192)
  const int mtile = blockIdx.y & 31;
  const int off0  = offs[e];
  const int Me    = offs[e + 1] - off0;
  const int m0    = mtile * 256;
  if (m0 >= Me) return;
  const int n0 = blockIdx.x * 256;
  const u16* We = W + (size_t)e * CDIM * CDIM;

  // [buf][A=0/B=1][chunk-plane][256*8 + 8 pad] u16  = 131584 B
  __shared__ u16 lds[4][2][4][2056];

  const int t    = threadIdx.x;
  const int lane = t & 63, wv = t >> 6;       // 8 waves
  const int wm = wv >> 2, wn = wv & 3;        // wave tile: rows wm*128, cols wn*64

  // ---- staging assignment: wave wv covers row-block rb (64 rows) x 2 chunks ----
  const int rb  = wv & 3;                     // 64-row block 0..3
  const int ch0 = (wv >> 2) * 2;              // chunks {ch0, ch0+1}
  const int arow = rb * 64 + lane;            // tile-row this lane stages (A and B)
  const int mr   = m0 + arow;
  const int rr   = (mr < Me) ? mr : (Me - 1); // clamp tail rows (dup loads, benign)
  const int ga   = (MODE == 0) ? tok_s[off0 + rr] : (off0 + rr);
  const u16* asrc = A  + (size_t)ga * CDIM;
  const u16* bsrc = We + (size_t)(n0 + arow) * CDIM;
  const int ldsrow8 = rb * 64 * 8;            // wave-uniform dest row offset (u16)

  #define STAGE(T_)                                                            \
    { const int bb_ = (T_) & 3; const int kk_ = (T_) * 32;                     \
      __builtin_amdgcn_global_load_lds(                                        \
          (const GLOBAL_AS void*)(asrc + kk_ + (ch0 + 0) * 8),                 \
          (LDS_AS void*)&lds[bb_][0][ch0 + 0][ldsrow8], 16, 0, 0);             \
      __builtin_amdgcn_global_load_lds(                                        \
          (const GLOBAL_AS void*)(asrc + kk_ + (ch0 + 1) * 8),                 \
          (LDS_AS void*)&lds[bb_][0][ch0 + 1][ldsrow8], 16, 0, 0);             \
      __builtin_amdgcn_global_load_lds(                                        \
          (const GLOBAL_AS void*)(bsrc + kk_ + (ch0 + 0) * 8),                 \
          (LDS_AS void*)&lds[bb_][1][ch0 + 0][ldsrow8], 16, 0, 0);             \
      __builtin_amdgcn_global_load_lds(                                        \
          (const GLOBAL_AS void*)(bsrc + kk_ + (ch0 + 1) * 8),                 \
          (LDS_AS void*)&lds[bb_][1][ch0 + 1][ldsrow8], 16, 0, 0); }

  f32x4 acc[8][4] = {};
  const int rsel = lane & 15;                 // row-within-16 for fragments
  const int g    = lane >> 4;                 // k-group -> chunk-plane
  f16x8 av[4], bv[4];

  #define MFMA16(mh_)                                                          \
    _Pragma("unroll")                                                          \
    for (int fi = 0; fi < 4; ++fi)                                             \
      _Pragma("unroll")                                                        \
      for (int fn = 0; fn < 4; ++fn)                                           \
        acc[(mh_) * 4 + fi][fn] = __builtin_amdgcn_mfma_f32_16x16x32_f16(      \
            av[fi], bv[fn], acc[(mh_) * 4 + fi][fn], 0, 0, 0);

  // Prologue: stage tiles 0,1,2 (12 loads/thread); wait tile 0 (drain to 8).
  STAGE(0); STAGE(1); STAGE(2);
  asm volatile("s_waitcnt vmcnt(8)" ::: "memory");
  __builtin_amdgcn_s_barrier();

  // Ledger (per thread, 4 loads/tile): enter iter T with {T+1,T+2} = 8 in
  // flight; STAGE(T+3) -> 12; vmcnt(8) at tile end retires exactly T+1's 4.
  #pragma unroll 4
  for (int T = 0; T < 64; ++T) {
    const int bb = T & 3;
    // ---- phase 0 (mh=0): 8 ds_read + stage + 16 MFMA ----
    #pragma unroll
    for (int fi = 0; fi < 4; ++fi)
      av[fi] = *(const f16x8*)&lds[bb][0][g][(wm * 128 + fi * 16 + rsel) * 8];
    #pragma unroll
    for (int fn = 0; fn < 4; ++fn)
      bv[fn] = *(const f16x8*)&lds[bb][1][g][(wn * 64 + fn * 16 + rsel) * 8];
    if (T <= 60) STAGE(T + 3);
    __builtin_amdgcn_s_barrier();
    asm volatile("s_waitcnt lgkmcnt(0)" ::: "memory");
    __builtin_amdgcn_sched_barrier(0);
    __builtin_amdgcn_s_setprio(1);
    MFMA16(0);
    __builtin_amdgcn_s_setprio(0);
    __builtin_amdgcn_sched_barrier(0);
    __builtin_amdgcn_s_barrier();
    // ---- phase 1 (mh=1): 4 ds_read (bv reused) + 16 MFMA ----
    #pragma unroll
    for (int fi = 0; fi < 4; ++fi)
      av[fi] = *(const f16x8*)&lds[bb][0][g][(wm * 128 + 64 + fi * 16 + rsel) * 8];
    __builtin_amdgcn_s_barrier();
    asm volatile("s_waitcnt lgkmcnt(0)" ::: "memory");
    __builtin_amdgcn_sched_barrier(0);
    __builtin_amdgcn_s_setprio(1);
    MFMA16(1);
    __builtin_amdgcn_s_setprio(0);
    __builtin_amdgcn_sched_barrier(0);
    if (T < 61)       { asm volatile("s_waitcnt vmcnt(8)" ::: "memory"); }
    else if (T == 61) { asm volatile("s_waitcnt vmcnt(4)" ::: "memory"); }
    else if (T == 62) { asm volatile("s_waitcnt vmcnt(0)" ::: "memory"); }
    __builtin_amdgcn_s_barrier();
  }
  #undef STAGE
  #undef MFMA16

  // Epilogue. C/D map: col = lane&15, row = (lane>>4)*4 + j.
  const int crow = g * 4;
  const int ccol = rsel;
  #pragma unroll
  for (int mh = 0; mh < 2; ++mh) {
    #pragma unroll
    for (int fi = 0; fi < 4; ++fi) {
      #pragma unroll
      for (int j = 0; j < 4; ++j) {
        const int r = m0 + wm * 128 + mh * 64 + fi * 16 + crow + j;
        if (r >= Me) continue;
        const int s = off0 + r;
        if (MODE == 0) {
          u16* hr = hout + (size_t)s * CDIM;
          #pragma unroll
          for (int fn = 0; fn < 4; ++fn) {
            float v = acc[mh * 4 + fi][fn][j];
            v = v > 0.f ? v * v : 0.f;                 // relu^2 fused
            hr[n0 + wn * 64 + fn * 16 + ccol] = f2h_bits(v);
          }
        } else {
          const float p = prb_s[s];
          float* orow = out + (size_t)tok_s[s] * CDIM;
          #pragma unroll
          for (int fn = 0; fn < 4; ++fn)
            atomicAdd(&orow[n0 + wn * 64 + fn * 16 + ccol], p * acc[mh * 4 + fi][fn][j]);
        }
      }
    }
  }
}

extern "C" void kernel_launch(void* const* d_in, const int* in_sizes, int n_in,
                              void* d_out, int out_size, void* d_ws, size_t ws_size,
                              hipStream_t stream)
{
  const float* x   = (const float*)d_in[0];
  const float* wr  = (const float*)d_in[1];
  const float* wfc = (const float*)d_in[2];
  const float* wpj = (const float*)d_in[3];
  float* out = (float*)d_out;
  char* ws = (char*)d_ws;

  const size_t OFF_TIDX = 256;
  const size_t OFF_TP   = OFF_TIDX + (size_t)NASS * 4;
  const size_t OFF_TOK  = OFF_TP   + (size_t)NASS * 4;
  const size_t OFF_PRB  = OFF_TOK  + (size_t)NASS * 4;
  const size_t OFF_XH   = (size_t)1 << 20;
  const size_t OFF_WFCT = OFF_XH   + (size_t)NTOK * CDIM * 2;
  const size_t OFF_WPJT = OFF_WFCT + (size_t)NEXP * CDIM * CDIM * 2;
  const size_t OFF_H    = OFF_WPJT + (size_t)NEXP * CDIM * CDIM * 2;
  const size_t NEED     = OFF_H    + (size_t)NASS * CDIM * 2;   // ~236 MB

  if (ws_size < NEED) {            // signal: absmax == |ref|max means ws too small
    hipMemsetAsync(d_out, 0, (size_t)out_size * 4, stream);
    return;
  }

  int*   counts = (int*)(ws + 0);
  int*   offs   = (int*)(ws + 64);
  int*   fill   = (int*)(ws + 128);
  int*   tidx   = (int*)(ws + OFF_TIDX);
  float* tp     = (float*)(ws + OFF_TP);
  int*   tok    = (int*)(ws + OFF_TOK);
  float* prb    = (float*)(ws + OFF_PRB);
  u16*   xh     = (u16*)(ws + OFF_XH);
  u16*   wfcT   = (u16*)(ws + OFF_WFCT);
  u16*   wpjT   = (u16*)(ws + OFF_WPJT);
  u16*   h      = (u16*)(ws + OFF_H);

  hipMemsetAsync(ws, 0, 256, stream);                       // counts/fill
  hipMemsetAsync(d_out, 0, (size_t)out_size * 4, stream);   // atomic target

  moe_router  <<<NTOK / 4, 256, 0, stream>>>(x, wr, xh, tidx, tp, counts);
  moe_offsets <<<1, 64, 0, stream>>>(counts, offs, fill);
  moe_scatter <<<NTOK / 256, 256, 0, stream>>>(tidx, tp, fill, tok, prb);
  moe_transpose<<<dim3(1024, NEXP, 2), 256, 0, stream>>>(wfc, wpj, wfcT, wpjT);
  moe_gemm3<0><<<dim3(8, NEXP * 32), 512, 0, stream>>>(xh, wfcT, tok, nullptr, offs, h, nullptr);
  moe_gemm3<1><<<dim3(8, NEXP * 32), 512, 0, stream>>>(h,  wpjT, tok, prb,     offs, nullptr, out);
}

// Round 4
// 812.769 us; speedup vs baseline: 1.2290x; 1.2290x over previous
//
#include <hip/hip_runtime.h>

typedef float   f32x4 __attribute__((ext_vector_type(4)));
typedef _Float16 f16x8 __attribute__((ext_vector_type(8)));
typedef short   s16x8 __attribute__((ext_vector_type(8)));
typedef short   s16x4 __attribute__((ext_vector_type(4)));
typedef unsigned short u16;

#define NTOK 8192
#define CDIM 2048
#define NEXP 8
#define NASS 16384   // NTOK * TOP_K

#define GLOBAL_AS __attribute__((address_space(1)))
#define LDS_AS    __attribute__((address_space(3)))

__device__ __forceinline__ u16 f2h_bits(float f) {
  _Float16 h = (_Float16)f;
  union { _Float16 h; u16 u; } v;
  v.h = h;
  return v.u;
}

// ---------- router: fp32 logits, top-2, softmax, counts, x -> f16 ----------
__global__ __launch_bounds__(256) void moe_router(
    const float* __restrict__ x, const float* __restrict__ wr,
    u16* __restrict__ xh, int* __restrict__ top_idx,
    float* __restrict__ top_p, int* __restrict__ counts)
{
  const int wave = threadIdx.x >> 6, lane = threadIdx.x & 63;
  const int n = blockIdx.x * 4 + wave;            // one wave per token
  const float* xr = x + (size_t)n * CDIM;
  u16* xhr = xh + (size_t)n * CDIM;
  float acc[NEXP] = {};
  #pragma unroll
  for (int i = 0; i < CDIM / 256; ++i) {
    const int c = i * 256 + lane * 4;
    const f32x4 xv = *(const f32x4*)(xr + c);
    s16x4 hv;
    #pragma unroll
    for (int j = 0; j < 4; ++j) hv[j] = (short)f2h_bits(xv[j]);
    *(s16x4*)(xhr + c) = hv;                      // fused x -> f16 (8B store)
    #pragma unroll
    for (int j = 0; j < 4; ++j) {
      const f32x4 w0 = *(const f32x4*)(wr + (size_t)(c + j) * NEXP);
      const f32x4 w1 = *(const f32x4*)(wr + (size_t)(c + j) * NEXP + 4);
      #pragma unroll
      for (int e = 0; e < 4; ++e) { acc[e] += xv[j] * w0[e]; acc[4 + e] += xv[j] * w1[e]; }
    }
  }
  #pragma unroll
  for (int off = 32; off > 0; off >>= 1) {
    #pragma unroll
    for (int e = 0; e < NEXP; ++e) acc[e] += __shfl_xor(acc[e], off);
  }
  if (lane == 0) {
    int i0 = 0; float v0 = acc[0];
    #pragma unroll
    for (int e = 1; e < NEXP; ++e) { if (acc[e] > v0) { v0 = acc[e]; i0 = e; } }
    int i1 = -1; float v1 = -3.4e38f;
    #pragma unroll
    for (int e = 0; e < NEXP; ++e) { if (e != i0 && acc[e] > v1) { v1 = acc[e]; i1 = e; } }
    const float ex = __expf(v1 - v0);             // softmax over the 2 kept logits
    const float p0 = 1.f / (1.f + ex);
    top_idx[n * 2 + 0] = i0; top_idx[n * 2 + 1] = i1;
    top_p[n * 2 + 0] = p0;   top_p[n * 2 + 1] = 1.f - p0;
    atomicAdd(&counts[i0], 1);
    atomicAdd(&counts[i1], 1);
  }
}

// ---------- exclusive scan of 8 counts ----------
__global__ void moe_offsets(const int* __restrict__ counts,
                            int* __restrict__ offs, int* __restrict__ fill)
{
  if (threadIdx.x == 0) {
    int s = 0;
    for (int e = 0; e < NEXP; ++e) { offs[e] = s; fill[e] = s; s += counts[e]; }
    offs[NEXP] = s;
  }
}

// ---------- scatter (token, prob) into expert buckets ----------
__global__ __launch_bounds__(256) void moe_scatter(
    const int* __restrict__ top_idx, const float* __restrict__ top_p,
    int* fill, int* __restrict__ tok_s, float* __restrict__ prb_s)
{
  const int n = blockIdx.x * 256 + threadIdx.x;
  #pragma unroll
  for (int k = 0; k < 2; ++k) {
    const int e = top_idx[n * 2 + k];
    const int pos = atomicAdd(&fill[e], 1);
    tok_s[pos] = n;
    prb_s[pos] = top_p[n * 2 + k];
  }
}

// ---------- transpose+convert: w [E][K][N] fp32 -> wT [E][N][K] f16 ----------
__global__ __launch_bounds__(256) void moe_transpose(
    const float* __restrict__ wfc, const float* __restrict__ wpj,
    u16* __restrict__ wfcT, u16* __restrict__ wpjT)
{
  const float* src = blockIdx.z ? wpj : wfc;
  u16* dst = blockIdx.z ? wpjT : wfcT;
  const int e = blockIdx.y;
  src += (size_t)e * CDIM * CDIM;
  dst += (size_t)e * CDIM * CDIM;
  const int tr = (blockIdx.x >> 5) * 64;   // src row (K) base
  const int tc = (blockIdx.x & 31) * 64;   // src col (N) base
  __shared__ float lds[64][65];            // +1 pad breaks bank conflicts
  const int t = threadIdx.x;
  #pragma unroll
  for (int p = 0; p < 4; ++p) {
    const int r  = p * 16 + (t >> 4);
    const int c4 = (t & 15) * 4;
    const f32x4 v = *(const f32x4*)(src + (size_t)(tr + r) * CDIM + tc + c4);
    #pragma unroll
    for (int j = 0; j < 4; ++j) lds[r][c4 + j] = v[j];
  }
  __syncthreads();
  const int d  = t >> 2;
  const int cs = (t & 3) * 16;
  s16x8 o0, o1;
  #pragma unroll
  for (int j = 0; j < 8; ++j) o0[j] = (short)f2h_bits(lds[cs + j][d]);
  #pragma unroll
  for (int j = 0; j < 8; ++j) o1[j] = (short)f2h_bits(lds[cs + 8 + j][d]);
  u16* drow = dst + (size_t)(tc + d) * CDIM + tr + cs;
  *(s16x8*)(drow + 0) = o0;
  *(s16x8*)(drow + 8) = o1;
}

// ---------- grouped GEMM: 128x256 tile, BK=32, dbuf 48KB -> 2 blocks/CU ----------
// 8 waves (2Mx4N), wave-tile 64x64, acc[4][4] (~120 unified regs/wave).
// Counted vmcnt(3) never drains; two independent blocks per CU overlap each
// other's stage/barrier stalls (m114 mechanism).
// LDS line-paired layout (BK=32 rows are 64B; pair rows per 128B line):
//   phys(r,c) = line (r>>1), slot (r&1)*4 + (c ^ ((r>>1)&3))  [slot=16B]
// -> staging is linear per global_load_lds (source k-chunk (l&3)^((l>>3)&3)),
//    and an 8-lane read run covers all 8 slots of a line bijectively
//    (structurally identical to R2's measured-zero-conflict pattern).
// MODE 0: H[s,:] = f16(relu(Xg @ WfcT^T)^2)   (A = xh gathered via tok_s)
// MODE 1: out[tok,:] += prb * (H @ WpjT^T)    (A = h linear; atomic combine)
template<int MODE>
__global__ __launch_bounds__(512, 4) void moe_gemm4(
    const u16* __restrict__ A, const u16* __restrict__ W,
    const int* __restrict__ tok_s, const float* __restrict__ prb_s,
    const int* __restrict__ offs, u16* __restrict__ hout,
    float* __restrict__ out)
{
  const int e     = blockIdx.y >> 6;          // 64 m-tiles per expert (Me <= 8192)
  const int mtile = blockIdx.y & 63;
  const int off0  = offs[e];
  const int Me    = offs[e + 1] - off0;
  const int m0    = mtile * 128;
  if (m0 >= Me) return;
  const int n0 = blockIdx.x * 256;
  const u16* We = W + (size_t)e * CDIM * CDIM;

  __shared__ u16 As[2][128 * 32];   // 8 KB x2
  __shared__ u16 Bs[2][256 * 32];   // 16 KB x2  -> 48 KB total

  const int t    = threadIdx.x;
  const int lane = t & 63, wv = t >> 6;       // 8 waves
  const int wm = wv >> 2, wn = wv & 3;        // wave-tile: rows wm*64, cols wn*64

  // ---- staging precompute (per lane) ----
  const int l     = lane;
  const int kchnk = (l & 3) ^ ((l >> 3) & 3); // source k-chunk for linear LDS fill
  const int kelem = kchnk * 8;
  const int rloc  = 2 * (l >> 3) + ((l >> 2) & 1);   // row within 16-row instr block
  // A: wave wv stages rows [wv*16, wv*16+16) (1 instr)
  {
  }
  const int rA  = wv * 16 + rloc;
  const int mrA = m0 + rA;
  const int rrA = (mrA < Me) ? mrA : (Me - 1);       // clamp tail (dup, benign)
  const int gaA = (MODE == 0) ? tok_s[off0 + rrA] : (off0 + rrA);
  const u16* asrc = A + (size_t)gaA * CDIM + kelem;
  // B: wave wv stages rows [wv*32, wv*32+32) (2 instrs)
  const int rB0 = wv * 32 + rloc;
  const int rB1 = wv * 32 + 16 + rloc;
  const u16* bsrc0 = We + (size_t)(n0 + rB0) * CDIM + kelem;
  const u16* bsrc1 = We + (size_t)(n0 + rB1) * CDIM + kelem;

  #define STAGE(T_)                                                            \
    { const int bb_ = (T_) & 1; const int kk_ = (T_) * 32;                     \
      __builtin_amdgcn_global_load_lds(                                        \
          (const GLOBAL_AS void*)(asrc + kk_),                                 \
          (LDS_AS void*)&As[bb_][wv * 512], 16, 0, 0);                         \
      __builtin_amdgcn_global_load_lds(                                        \
          (const GLOBAL_AS void*)(bsrc0 + kk_),                                \
          (LDS_AS void*)&Bs[bb_][wv * 1024], 16, 0, 0);                        \
      __builtin_amdgcn_global_load_lds(                                        \
          (const GLOBAL_AS void*)(bsrc1 + kk_),                                \
          (LDS_AS void*)&Bs[bb_][wv * 1024 + 512], 16, 0, 0); }

  // ---- read addressing (per lane) ----
  const int rsel     = lane & 15;
  const int g        = lane >> 4;
  const int halfline = rsel >> 1;
  const int slotx    = (((rsel & 1) * 4) + (g ^ (halfline & 3))) * 8;  // u16 units

  f32x4 acc[4][4] = {};

  #define COMPUTE(bb)                                                          \
    { f16x8 bv[4];                                                             \
      _Pragma("unroll")                                                        \
      for (int fn = 0; fn < 4; ++fn)                                           \
        bv[fn] = *(const f16x8*)&Bs[bb][(wn * 32 + fn * 8 + halfline) * 64 + slotx]; \
      _Pragma("unroll")                                                        \
      for (int fi = 0; fi < 4; ++fi) {                                         \
        const f16x8 av = *(const f16x8*)&As[bb][(wm * 32 + fi * 8 + halfline) * 64 + slotx]; \
        _Pragma("unroll")                                                      \
        for (int fn = 0; fn < 4; ++fn)                                         \
          acc[fi][fn] = __builtin_amdgcn_mfma_f32_16x16x32_f16(                \
              av, bv[fn], acc[fi][fn], 0, 0, 0);                               \
      } }

  // Ledger (3 loads/thread/tile): steady outstanding at vmcnt = T(3)+T+1(3)=6;
  // vmcnt(3) retires exactly tile T, keeps T+1 in flight -> never drains.
  STAGE(0);
  #pragma unroll 2
  for (int T = 0; T < 63; ++T) {
    STAGE(T + 1);
    asm volatile("s_waitcnt vmcnt(3)" ::: "memory");
    __builtin_amdgcn_s_barrier();
    COMPUTE(T & 1);
    __builtin_amdgcn_s_barrier();
  }
  asm volatile("s_waitcnt vmcnt(0)" ::: "memory");
  __builtin_amdgcn_s_barrier();
  COMPUTE(1);

  #undef STAGE
  #undef COMPUTE

  // Epilogue. C/D map: col = lane&15, row = (lane>>4)*4 + j.
  const int crow = g * 4;
  const int ccol = rsel;
  #pragma unroll
  for (int fi = 0; fi < 4; ++fi) {
    #pragma unroll
    for (int j = 0; j < 4; ++j) {
      const int r = m0 + wm * 64 + fi * 16 + crow + j;
      if (r >= Me) continue;
      const int s = off0 + r;
      if (MODE == 0) {
        u16* hr = hout + (size_t)s * CDIM;
        #pragma unroll
        for (int fn = 0; fn < 4; ++fn) {
          float v = acc[fi][fn][j];
          v = v > 0.f ? v * v : 0.f;                  // relu^2 fused
          hr[n0 + wn * 64 + fn * 16 + ccol] = f2h_bits(v);
        }
      } else {
        const float p = prb_s[s];
        float* orow = out + (size_t)tok_s[s] * CDIM;
        #pragma unroll
        for (int fn = 0; fn < 4; ++fn)
          atomicAdd(&orow[n0 + wn * 64 + fn * 16 + ccol], p * acc[fi][fn][j]);
      }
    }
  }
}

extern "C" void kernel_launch(void* const* d_in, const int* in_sizes, int n_in,
                              void* d_out, int out_size, void* d_ws, size_t ws_size,
                              hipStream_t stream)
{
  const float* x   = (const float*)d_in[0];
  const float* wr  = (const float*)d_in[1];
  const float* wfc = (const float*)d_in[2];
  const float* wpj = (const float*)d_in[3];
  float* out = (float*)d_out;
  char* ws = (char*)d_ws;

  const size_t OFF_TIDX = 256;
  const size_t OFF_TP   = OFF_TIDX + (size_t)NASS * 4;
  const size_t OFF_TOK  = OFF_TP   + (size_t)NASS * 4;
  const size_t OFF_PRB  = OFF_TOK  + (size_t)NASS * 4;
  const size_t OFF_XH   = (size_t)1 << 20;
  const size_t OFF_WFCT = OFF_XH   + (size_t)NTOK * CDIM * 2;
  const size_t OFF_WPJT = OFF_WFCT + (size_t)NEXP * CDIM * CDIM * 2;
  const size_t OFF_H    = OFF_WPJT + (size_t)NEXP * CDIM * CDIM * 2;
  const size_t NEED     = OFF_H    + (size_t)NASS * CDIM * 2;   // ~236 MB

  if (ws_size < NEED) {            // signal: absmax == |ref|max means ws too small
    hipMemsetAsync(d_out, 0, (size_t)out_size * 4, stream);
    return;
  }

  int*   counts = (int*)(ws + 0);
  int*   offs   = (int*)(ws + 64);
  int*   fill   = (int*)(ws + 128);
  int*   tidx   = (int*)(ws + OFF_TIDX);
  float* tp     = (float*)(ws + OFF_TP);
  int*   tok    = (int*)(ws + OFF_TOK);
  float* prb    = (float*)(ws + OFF_PRB);
  u16*   xh     = (u16*)(ws + OFF_XH);
  u16*   wfcT   = (u16*)(ws + OFF_WFCT);
  u16*   wpjT   = (u16*)(ws + OFF_WPJT);
  u16*   h      = (u16*)(ws + OFF_H);

  hipMemsetAsync(ws, 0, 256, stream);                       // counts/fill
  hipMemsetAsync(d_out, 0, (size_t)out_size * 4, stream);   // atomic target

  moe_router  <<<NTOK / 4, 256, 0, stream>>>(x, wr, xh, tidx, tp, counts);
  moe_offsets <<<1, 64, 0, stream>>>(counts, offs, fill);
  moe_scatter <<<NTOK / 256, 256, 0, stream>>>(tidx, tp, fill, tok, prb);
  moe_transpose<<<dim3(1024, NEXP, 2), 256, 0, stream>>>(wfc, wpj, wfcT, wpjT);
  moe_gemm4<0><<<dim3(8, NEXP * 64), 512, 0, stream>>>(xh, wfcT, tok, nullptr, offs, h, nullptr);
  moe_gemm4<1><<<dim3(8, NEXP * 64), 512, 0, stream>>>(h,  wpjT, tok, prb,     offs, nullptr, out);
}